// Round 2
// baseline (243.011 us; speedup 1.0000x reference)
//
#include <hip/hip_runtime.h>
#include <hip/hip_bf16.h>
#include <math.h>

typedef short bf16x8 __attribute__((ext_vector_type(8)));
typedef float f32x4 __attribute__((ext_vector_type(4)));

constexpr int CIN = 32, COUT = 64, D = 16, H = 32, W = 32;

// ---------------- ws layout ----------------
// [0, 884736) : wtp bf16 [cls8][t27][co64][ci32]
constexpr size_t WS_NEED = 884736u;

// Per-wave item lists (full-co): item = (cls, alpha), code = cls + alpha*8.
static __device__ const unsigned char IT_CODE[24] = {
    0, 8, 16, 3,                  // w0 (93 taps)
    1, 9, 17, 11, 19, 7,          // w1 (86)
    2, 10, 18, 5, 13, 21, 15,     // w2 (98)
    4, 12, 20, 6, 14, 22, 23};    // w3 (98)
static __device__ const unsigned char IT_START[5] = {0, 4, 10, 17, 24};
// 5 local windows per half-block; e-slot = quad*2 + part
static __device__ const unsigned char EPI_START[5] = {0, 1, 3, 5, 6};
static __device__ const unsigned char EPI_CNT[5]   = {1, 2, 2, 1, 1};

__global__ void prep_w(const float* __restrict__ w, unsigned short* __restrict__ wtp) {
    int idx = blockIdx.x * 256 + threadIdx.x;            // 442368 total
    int ci  = idx & 31;
    int co  = (idx >> 5) & 63;
    int tt  = idx >> 11;                                  // cls*27 + t
    int t   = tt % 27, cls = tt / 27;
    int td = t / 9, th = (t / 3) % 3, tw = t % 3;
    int pd = (cls >> 2) & 1, ph = (cls >> 1) & 1, pw = cls & 1;
    int kd = pd + 2 * td, kh = ph + 2 * th, kw = pw + 2 * tw;
    float v = 0.f;
    if (kd < 5 && kh < 5 && kw < 5)
        v = w[(ci * COUT + co) * 125 + kd * 25 + kh * 5 + kw];
    __hip_bfloat16 b = __float2bfloat16(v);
    wtp[idx] = *reinterpret_cast<unsigned short*>(&b);
}

__device__ __forceinline__ int lpA(int wrow, int quad) {
    return wrow * 64 + ((quad ^ ((wrow >> 1) & 3)) << 4);
}

__global__ __launch_bounds__(256, 3) void main_k(
    const unsigned short* __restrict__ wtp, const float* __restrict__ x,
    const float* __restrict__ bias, float* __restrict__ out)
{
    __shared__ unsigned short Xs[25600];   // 51200 B, granule-XOR swizzled
    int bx   = blockIdx.x;                 // ((n*5+d0)*10 + h0)*2 + half, 1600 total
    int half = bx & 1;
    int obx  = bx >> 1;
    int h0 = obx % 10;
    int d0 = (obx / 10) % 5;
    int n  = obx / 50;
    int tid = threadIdx.x;

    // ---- stage Xs (only the w-columns this half reads) ----
    // half0 reads ww 0..17 -> stage q 0..4 (+pad col 0); half1 reads ww 15..31 -> q 3..7
    int id0 = 3 * d0 - 1, ih0 = 3 * h0 - 1;
    int qb = half ? 3 : 0;
    for (int u = tid; u < 4000; u += 256) {
        int qi = u % 5;
        int t2 = u / 5;
        int ci = t2 & 31;
        int p  = t2 >> 5;          // dd*5+hl, 0..24
        int q  = qb + qi;
        int dd = p / 5, hl = p % 5;
        int id = id0 + dd, ih = ih0 + hl;
        float4 v = {0.f, 0.f, 0.f, 0.f};
        if (id >= 0 && ih >= 0)
            v = ((const float4*)(x + (((size_t)(n * CIN + ci) * D + id) * H + ih) * W))[q];
        unsigned short hj[4];
        {
            __hip_bfloat16 b0 = __float2bfloat16(v.x); hj[0] = *reinterpret_cast<unsigned short*>(&b0);
            __hip_bfloat16 b1 = __float2bfloat16(v.y); hj[1] = *reinterpret_cast<unsigned short*>(&b1);
            __hip_bfloat16 b2 = __float2bfloat16(v.z); hj[2] = *reinterpret_cast<unsigned short*>(&b2);
            __hip_bfloat16 b3 = __float2bfloat16(v.w); hj[3] = *reinterpret_cast<unsigned short*>(&b3);
        }
        int rowb = p * 1024;
        int cig = ci >> 3, cil = ci & 7;
#pragma unroll
        for (int j = 0; j < 4; ++j) {
            int ww = 4 * q + 1 + j;
            if (ww < 32)
                Xs[rowb + ww * 32 + ((cig ^ ((ww >> 1) & 3)) << 3) + cil] = hj[j];
        }
        if (q == 0)
            Xs[rowb + (cig << 3) + cil] = 0;   // ww=0 (iw=-1) zero pad (half0 only)
    }

    int lane = tid & 63, wv = tid >> 6;
    int l15 = lane & 15, quad = lane >> 4;
    int wv_s = __builtin_amdgcn_readfirstlane(wv);

    int laneB = l15 * 64 + quad * 16;
    int mtmp = 15 + l15;
    int mb = half ? (mtmp > 29 ? 29 : mtmp) : l15;        // M-tile base row (clamped dup for half1)
    int lp0 = lpA(mb + 0, quad), lp1 = lpA(mb + 1, quad), lp2 = lpA(mb + 2, quad);

    float mxp[4][2];
#pragma unroll
    for (int nt = 0; nt < 4; ++nt) { mxp[nt][0] = -INFINITY; mxp[nt][1] = -INFINITY; }

    __syncthreads();
    const char* xsb = (const char*)Xs;

    int fsm = half ? 0x4123 : 0x3123;
    int fs  = (fsm >> (quad * 4)) & 15;

    int it0 = IT_START[wv_s], it1 = IT_START[wv_s + 1];
#pragma unroll 1
    for (int ii = it0; ii < it1; ++ii) {
        int code  = __builtin_amdgcn_readfirstlane(IT_CODE[ii]);
        int cls   = code & 7;
        int alpha = code >> 3;
        int ntd = 3 - ((cls >> 2) & 1), nth = 3 - ((cls >> 1) & 1), ntw = 3 - (cls & 1);
        const char* tbb = (const char*)wtp + (size_t)cls * 27 * 4096 + laneB;
        const int T = ntd * nth * ntw;   // >= 8 always

        f32x4 acc[3][4];
#pragma unroll
        for (int b = 0; b < 3; ++b)
#pragma unroll
            for (int nt = 0; nt < 4; ++nt) acc[b][nt] = (f32x4){0.f, 0.f, 0.f, 0.f};

        int ptd = 0, pth = 0, ptw = 0;   // state = next unissued tap
        auto adv = [&]() {
            ++ptw;
            if (ptw == ntw) { ptw = 0; ++pth; if (pth == nth) { pth = 0; ++ptd; } }
        };

        // ---- prologue: tap 0 (E) ----
        bf16x8 bE0, bE1, bE2, bE3, aE0, aE1, aE2;
        {
            int Qb = ((alpha + 2) * 5 + 2) * 2048;        // ss = 2
            bE0 = *(const bf16x8*)(tbb);
            bE1 = *(const bf16x8*)(tbb + 1024);
            bE2 = *(const bf16x8*)(tbb + 2048);
            bE3 = *(const bf16x8*)(tbb + 3072);
            const char* rb = xsb + Qb;
            aE0 = *(const bf16x8*)(rb + lp2);
            aE1 = *(const bf16x8*)(rb + 2048 + lp2);
            aE2 = *(const bf16x8*)(rb + 4096 + lp2);
        }
        adv();
        // ---- tap 1 (O) ----
        bf16x8 bO0, bO1, bO2, bO3, aO0, aO1, aO2;
        {
            int Qb = ((alpha + 2 - ptd) * 5 + (2 - pth)) * 2048;
            int ss = 2 - ptw;
            const char* bq = tbb + (ptd * 9 + pth * 3 + ptw) * 4096;
            bO0 = *(const bf16x8*)(bq);
            bO1 = *(const bf16x8*)(bq + 1024);
            bO2 = *(const bf16x8*)(bq + 2048);
            bO3 = *(const bf16x8*)(bq + 3072);
            int lpx = ss == 0 ? lp0 : (ss == 1 ? lp1 : lp2);
            const char* rb = xsb + Qb;
            aO0 = *(const bf16x8*)(rb + lpx);
            aO1 = *(const bf16x8*)(rb + 2048 + lpx);
            aO2 = *(const bf16x8*)(rb + 4096 + lpx);
        }
        adv();

#pragma unroll 1
        for (int it = 0; it < T; it += 2) {
            // ---- consume E (tap it) ----
            __builtin_amdgcn_s_setprio(1);
            acc[0][0] = __builtin_amdgcn_mfma_f32_16x16x32_bf16(aE0, bE0, acc[0][0], 0, 0, 0);
            acc[0][1] = __builtin_amdgcn_mfma_f32_16x16x32_bf16(aE0, bE1, acc[0][1], 0, 0, 0);
            acc[0][2] = __builtin_amdgcn_mfma_f32_16x16x32_bf16(aE0, bE2, acc[0][2], 0, 0, 0);
            acc[0][3] = __builtin_amdgcn_mfma_f32_16x16x32_bf16(aE0, bE3, acc[0][3], 0, 0, 0);
            acc[1][0] = __builtin_amdgcn_mfma_f32_16x16x32_bf16(aE1, bE0, acc[1][0], 0, 0, 0);
            acc[1][1] = __builtin_amdgcn_mfma_f32_16x16x32_bf16(aE1, bE1, acc[1][1], 0, 0, 0);
            acc[1][2] = __builtin_amdgcn_mfma_f32_16x16x32_bf16(aE1, bE2, acc[1][2], 0, 0, 0);
            acc[1][3] = __builtin_amdgcn_mfma_f32_16x16x32_bf16(aE1, bE3, acc[1][3], 0, 0, 0);
            acc[2][0] = __builtin_amdgcn_mfma_f32_16x16x32_bf16(aE2, bE0, acc[2][0], 0, 0, 0);
            acc[2][1] = __builtin_amdgcn_mfma_f32_16x16x32_bf16(aE2, bE1, acc[2][1], 0, 0, 0);
            acc[2][2] = __builtin_amdgcn_mfma_f32_16x16x32_bf16(aE2, bE2, acc[2][2], 0, 0, 0);
            acc[2][3] = __builtin_amdgcn_mfma_f32_16x16x32_bf16(aE2, bE3, acc[2][3], 0, 0, 0);
            __builtin_amdgcn_s_setprio(0);
            if (it + 2 < T) {     // re-issue E for tap it+2
                int Qb = ((alpha + 2 - ptd) * 5 + (2 - pth)) * 2048;
                int ss = 2 - ptw;
                const char* bq = tbb + (ptd * 9 + pth * 3 + ptw) * 4096;
                bE0 = *(const bf16x8*)(bq);
                bE1 = *(const bf16x8*)(bq + 1024);
                bE2 = *(const bf16x8*)(bq + 2048);
                bE3 = *(const bf16x8*)(bq + 3072);
                int lpx = ss == 0 ? lp0 : (ss == 1 ? lp1 : lp2);
                const char* rb = xsb + Qb;
                aE0 = *(const bf16x8*)(rb + lpx);
                aE1 = *(const bf16x8*)(rb + 2048 + lpx);
                aE2 = *(const bf16x8*)(rb + 4096 + lpx);
                adv();
            }
            if (it + 1 < T) {
                // ---- consume O (tap it+1) ----
                __builtin_amdgcn_s_setprio(1);
                acc[0][0] = __builtin_amdgcn_mfma_f32_16x16x32_bf16(aO0, bO0, acc[0][0], 0, 0, 0);
                acc[0][1] = __builtin_amdgcn_mfma_f32_16x16x32_bf16(aO0, bO1, acc[0][1], 0, 0, 0);
                acc[0][2] = __builtin_amdgcn_mfma_f32_16x16x32_bf16(aO0, bO2, acc[0][2], 0, 0, 0);
                acc[0][3] = __builtin_amdgcn_mfma_f32_16x16x32_bf16(aO0, bO3, acc[0][3], 0, 0, 0);
                acc[1][0] = __builtin_amdgcn_mfma_f32_16x16x32_bf16(aO1, bO0, acc[1][0], 0, 0, 0);
                acc[1][1] = __builtin_amdgcn_mfma_f32_16x16x32_bf16(aO1, bO1, acc[1][1], 0, 0, 0);
                acc[1][2] = __builtin_amdgcn_mfma_f32_16x16x32_bf16(aO1, bO2, acc[1][2], 0, 0, 0);
                acc[1][3] = __builtin_amdgcn_mfma_f32_16x16x32_bf16(aO1, bO3, acc[1][3], 0, 0, 0);
                acc[2][0] = __builtin_amdgcn_mfma_f32_16x16x32_bf16(aO2, bO0, acc[2][0], 0, 0, 0);
                acc[2][1] = __builtin_amdgcn_mfma_f32_16x16x32_bf16(aO2, bO1, acc[2][1], 0, 0, 0);
                acc[2][2] = __builtin_amdgcn_mfma_f32_16x16x32_bf16(aO2, bO2, acc[2][2], 0, 0, 0);
                acc[2][3] = __builtin_amdgcn_mfma_f32_16x16x32_bf16(aO2, bO3, acc[2][3], 0, 0, 0);
                __builtin_amdgcn_s_setprio(0);
                if (it + 3 < T) {   // re-issue O for tap it+3
                    int Qb = ((alpha + 2 - ptd) * 5 + (2 - pth)) * 2048;
                    int ss = 2 - ptw;
                    const char* bq = tbb + (ptd * 9 + pth * 3 + ptw) * 4096;
                    bO0 = *(const bf16x8*)(bq);
                    bO1 = *(const bf16x8*)(bq + 1024);
                    bO2 = *(const bf16x8*)(bq + 2048);
                    bO3 = *(const bf16x8*)(bq + 3072);
                    int lpx = ss == 0 ? lp0 : (ss == 1 ? lp1 : lp2);
                    const char* rb = xsb + Qb;
                    aO0 = *(const bf16x8*)(rb + lpx);
                    aO1 = *(const bf16x8*)(rb + 2048 + lpx);
                    aO2 = *(const bf16x8*)(rb + 4096 + lpx);
                    adv();
                }
            }
        }

        // fold item directly into per-window partials (same mapping every item)
#pragma unroll
        for (int nt = 0; nt < 4; ++nt) {
            float r0 = fmaxf(fmaxf(acc[0][nt][0], acc[1][nt][0]), acc[2][nt][0]);
            float r1 = fmaxf(fmaxf(acc[0][nt][1], acc[1][nt][1]), acc[2][nt][1]);
            float r2 = fmaxf(fmaxf(acc[0][nt][2], acc[1][nt][2]), acc[2][nt][2]);
            float r3 = fmaxf(fmaxf(acc[0][nt][3], acc[1][nt][3]), acc[2][nt][3]);
            float t01 = fmaxf(r0, r1), t012 = fmaxf(t01, r2), t0123 = fmaxf(t012, r3);
            float pA = fs == 1 ? r0 : (fs == 2 ? t01 : (fs == 3 ? t012 : t0123));
            float t23 = fmaxf(r2, r3), t123 = fmaxf(r1, t23);
            float pB = fs == 1 ? t123 : (fs == 2 ? t23 : (fs == 3 ? r3 : -INFINITY));
            mxp[nt][0] = fmaxf(mxp[nt][0], pA);
            mxp[nt][1] = fmaxf(mxp[nt][1], pB);
        }
    }

    // ---- epilogue: cross-wave max, bias, co-sum ----
    __syncthreads();                 // Xs reads done; reuse as epi buffer
    float* epi = (float*)Xs;         // 4 waves x 8 e-slots x 64 co = 8 KiB
#pragma unroll
    for (int nt = 0; nt < 4; ++nt) {
        epi[(wv * 8 + quad * 2 + 0) * 64 + nt * 16 + l15] = mxp[nt][0];
        epi[(wv * 8 + quad * 2 + 1) * 64 + nt * 16 + l15] = mxp[nt][1];
    }
    __syncthreads();

    int elemBase = ((n * 5 + d0) * 10 + h0) * 10 + half * 5;
    float bco = bias[lane];
#pragma unroll 1
    for (int winl = wv_s; winl < 5; winl += 4) {
        int st = EPI_START[winl], cnt = EPI_CNT[winl];
        float v = -INFINITY;
        for (int src = 0; src < 4; ++src)
            for (int e = st; e < st + cnt; ++e)
                v = fmaxf(v, epi[(src * 8 + e) * 64 + lane]);
        v += bco;
#pragma unroll
        for (int off = 32; off > 0; off >>= 1) v += __shfl_xor(v, off);
        if (lane == 0) out[elemBase + winl] = v;
    }
}

// ---------------- fallback (round-1 kernel, no ws needed) ----------------
__global__ __launch_bounds__(256) void fused_fallback(
    const float* __restrict__ x, const float* __restrict__ wsrc,
    const float* __restrict__ bias, float* __restrict__ out)
{
    __shared__ float xs[CIN * 125];
    __shared__ float wmax[4][64];
    const int b  = blockIdx.x;
    const int w0 = b % 10, h0 = (b / 10) % 10, d0 = (b / 100) % 5, n = b / 500;
    const int tid = threadIdx.x;
    const int id0 = 3 * d0 - 1, ih0 = 3 * h0 - 1, iw0 = 3 * w0 - 1;
    for (int e = tid; e < CIN * 125; e += 256) {
        int kk = e % 5, jj = (e / 5) % 5, ii = (e / 25) % 5, c = e / 125;
        int id = id0 + ii, ih = ih0 + jj, iw = iw0 + kk;
        float v = 0.f;
        if (id >= 0 && ih >= 0 && iw >= 0)
            v = x[(((n * CIN + c) * D + id) * H + ih) * W + iw];
        xs[e] = v;
    }
    __syncthreads();
    const int lane = tid & 63, wv = tid >> 6;
    float lmax = -INFINITY;
    for (int ccls = 0; ccls < 2; ++ccls) {
        const int cls = wv * 2 + ccls;
        const int pd = (cls >> 2) & 1, ph = (cls >> 1) & 1, pw = cls & 1;
        float acc[27];
#pragma unroll
        for (int i = 0; i < 27; ++i) acc[i] = 0.f;
        for (int ci = 0; ci < CIN; ++ci) {
            float wr[27];
#pragma unroll
            for (int t = 0; t < 27; ++t) {
                int td = t / 9, th = (t / 3) % 3, tw = t % 3;
                int kd = pd + 2 * td, kh = ph + 2 * th, kw = pw + 2 * tw;
                wr[t] = (kd < 5 && kh < 5 && kw < 5)
                          ? wsrc[((ci * 64 + lane) * 125) + kd * 25 + kh * 5 + kw] : 0.f;
            }
            const float* xb = xs + ci * 125;
#pragma unroll
            for (int td = 0; td < 3; ++td)
#pragma unroll
            for (int th = 0; th < 3; ++th)
#pragma unroll
            for (int tw = 0; tw < 3; ++tw) {
                const float wval = wr[(td * 3 + th) * 3 + tw];
#pragma unroll
                for (int a = 0; a < 3; ++a)
#pragma unroll
                for (int bb = 0; bb < 3; ++bb)
#pragma unroll
                for (int cc = 0; cc < 3; ++cc)
                    acc[(a * 3 + bb) * 3 + cc] +=
                        xb[(a + 2 - td) * 25 + (bb + 2 - th) * 5 + (cc + 2 - tw)] * wval;
            }
        }
#pragma unroll
        for (int i = 0; i < 27; ++i) lmax = fmaxf(lmax, acc[i]);
    }
    wmax[wv][lane] = lmax;
    __syncthreads();
    if (wv == 0) {
        float m = fmaxf(fmaxf(wmax[0][lane], wmax[1][lane]),
                        fmaxf(wmax[2][lane], wmax[3][lane]));
        m += bias[lane];
        for (int off = 32; off > 0; off >>= 1) m += __shfl_down(m, off);
        if (lane == 0) out[b] = m;
    }
}

extern "C" void kernel_launch(void* const* d_in, const int* in_sizes, int n_in,
                              void* d_out, int out_size, void* d_ws, size_t ws_size,
                              hipStream_t stream) {
    const float* x    = (const float*)d_in[0];
    const float* w    = (const float*)d_in[1];
    const float* bias = (const float*)d_in[2];
    float* out = (float*)d_out;

    if (ws_size >= WS_NEED) {
        unsigned short* wtp = (unsigned short*)d_ws;
        prep_w<<<1728, 256, 0, stream>>>(w, wtp);
        main_k<<<1600, 256, 0, stream>>>(wtp, x, bias, out);
    } else {
        fused_fallback<<<8000, 256, 0, stream>>>(x, w, bias, out);
    }
}

// Round 3
// 201.148 us; speedup vs baseline: 1.2081x; 1.2081x over previous
//
#include <hip/hip_runtime.h>
#include <hip/hip_bf16.h>
#include <math.h>

typedef short bf16x8 __attribute__((ext_vector_type(8)));
typedef float f32x4 __attribute__((ext_vector_type(4)));

constexpr int CIN = 32, COUT = 64, D = 16, H = 32, W = 32;

// ---------------- ws layout ----------------
// [0, 884736) : wtp bf16 [cls8][t27][co64][ci32]
constexpr size_t WS_NEED = 884736u;

// Per-wave item lists (full-co): item = (cls, alpha), code = cls + alpha*8.
static __device__ const unsigned char IT_CODE[24] = {
    0, 8, 16, 3,                  // w0 (93 taps)
    1, 9, 17, 11, 19, 7,          // w1 (86)
    2, 10, 18, 5, 13, 21, 15,     // w2 (98)
    4, 12, 20, 6, 14, 22, 23};    // w3 (98)
static __device__ const unsigned char IT_START[5] = {0, 4, 10, 17, 24};
static __device__ const unsigned char EPI_START[10] = {0, 1, 3, 5, 6, 7, 9, 11, 12, 13};
static __device__ const unsigned char EPI_CNT[10]   = {1, 2, 2, 1, 1, 2, 2, 1, 1, 2};

__global__ void prep_w(const float* __restrict__ w, unsigned short* __restrict__ wtp) {
    int idx = blockIdx.x * 256 + threadIdx.x;            // 442368 total
    int ci  = idx & 31;
    int co  = (idx >> 5) & 63;
    int tt  = idx >> 11;                                  // cls*27 + t
    int t   = tt % 27, cls = tt / 27;
    int td = t / 9, th = (t / 3) % 3, tw = t % 3;
    int pd = (cls >> 2) & 1, ph = (cls >> 1) & 1, pw = cls & 1;
    int kd = pd + 2 * td, kh = ph + 2 * th, kw = pw + 2 * tw;
    float v = 0.f;
    if (kd < 5 && kh < 5 && kw < 5)
        v = w[(ci * COUT + co) * 125 + kd * 25 + kh * 5 + kw];
    __hip_bfloat16 b = __float2bfloat16(v);
    wtp[idx] = *reinterpret_cast<unsigned short*>(&b);
}

__device__ __forceinline__ int lpA(int wrow, int quad) {
    return wrow * 64 + ((quad ^ ((wrow >> 1) & 3)) << 4);
}

#define MFMA_G(nt, bb)                                                                       \
    acc[0][0][nt] = __builtin_amdgcn_mfma_f32_16x16x32_bf16(a##bb##0, b##bb##nt, acc[0][0][nt], 0, 0, 0); \
    acc[0][1][nt] = __builtin_amdgcn_mfma_f32_16x16x32_bf16(a##bb##1, b##bb##nt, acc[0][1][nt], 0, 0, 0); \
    acc[1][0][nt] = __builtin_amdgcn_mfma_f32_16x16x32_bf16(a##bb##2, b##bb##nt, acc[1][0][nt], 0, 0, 0); \
    acc[1][1][nt] = __builtin_amdgcn_mfma_f32_16x16x32_bf16(a##bb##3, b##bb##nt, acc[1][1][nt], 0, 0, 0); \
    acc[2][0][nt] = __builtin_amdgcn_mfma_f32_16x16x32_bf16(a##bb##4, b##bb##nt, acc[2][0][nt], 0, 0, 0); \
    acc[2][1][nt] = __builtin_amdgcn_mfma_f32_16x16x32_bf16(a##bb##5, b##bb##nt, acc[2][1][nt], 0, 0, 0);

__global__ __launch_bounds__(256, 2) void main_k(
    const unsigned short* __restrict__ wtp, const float* __restrict__ x,
    const float* __restrict__ bias, float* __restrict__ out)
{
    __shared__ unsigned short Xs[25600];   // 51200 B, granule-XOR swizzled
    int bx = blockIdx.x;                   // (n*5+d0)*10 + h0, 800 total
    int h0 = bx % 10;
    int d0 = (bx / 10) % 5;
    int n  = bx / 50;
    int tid = threadIdx.x;

    // ---- stage Xs directly from x (fp32 -> bf16, transpose, swizzle) ----
    int id0 = 3 * d0 - 1, ih0 = 3 * h0 - 1;
#pragma unroll 5
    for (int u = tid; u < 6400; u += 256) {
        int q  = u & 7;            // float4 index: iw = 4q..4q+3
        int ci = (u >> 3) & 31;
        int p  = u >> 8;           // dd*5+hl
        int dd = p / 5, hl = p % 5;
        int id = id0 + dd, ih = ih0 + hl;
        float4 v = {0.f, 0.f, 0.f, 0.f};
        if (id >= 0 && ih >= 0)
            v = ((const float4*)(x + (((size_t)(n * CIN + ci) * D + id) * H + ih) * W))[q];
        unsigned short hj[4];
        {
            __hip_bfloat16 b0 = __float2bfloat16(v.x); hj[0] = *reinterpret_cast<unsigned short*>(&b0);
            __hip_bfloat16 b1 = __float2bfloat16(v.y); hj[1] = *reinterpret_cast<unsigned short*>(&b1);
            __hip_bfloat16 b2 = __float2bfloat16(v.z); hj[2] = *reinterpret_cast<unsigned short*>(&b2);
            __hip_bfloat16 b3 = __float2bfloat16(v.w); hj[3] = *reinterpret_cast<unsigned short*>(&b3);
        }
        int rowb = p * 1024;
        int cig = ci >> 3, cil = ci & 7;
#pragma unroll
        for (int j = 0; j < 4; ++j) {
            int ww = 4 * q + 1 + j;
            if (ww < 32)
                Xs[rowb + ww * 32 + ((cig ^ ((ww >> 1) & 3)) << 3) + cil] = hj[j];
        }
        if (q == 0)
            Xs[rowb + (cig << 3) + cil] = 0;   // ww=0 (iw=-1) zero pad
    }

    int lane = tid & 63, wv = tid >> 6;
    int l15 = lane & 15, quad = lane >> 4;
    int wv_s = __builtin_amdgcn_readfirstlane(wv);

    int laneB = l15 * 64 + quad * 16;
    int m1 = 16 + l15; if (m1 > 29) m1 = 29;
    int lp00 = lpA(l15 + 0, quad), lp01 = lpA(l15 + 1, quad), lp02 = lpA(l15 + 2, quad);
    int lp10 = lpA(m1 + 0, quad),  lp11 = lpA(m1 + 1, quad),  lp12 = lpA(m1 + 2, quad);

    f32x4 mx[2][4];
#pragma unroll
    for (int mt = 0; mt < 2; ++mt)
#pragma unroll
        for (int nt = 0; nt < 4; ++nt) mx[mt][nt] = (f32x4){-INFINITY, -INFINITY, -INFINITY, -INFINITY};

    __syncthreads();
    const char* xsb = (const char*)Xs;

    int it0 = IT_START[wv_s], it1 = IT_START[wv_s + 1];
#pragma unroll 1
    for (int ii = it0; ii < it1; ++ii) {
        int code  = __builtin_amdgcn_readfirstlane(IT_CODE[ii]);
        int cls   = code & 7;
        int alpha = code >> 3;
        int ntd = 3 - ((cls >> 2) & 1), nth = 3 - ((cls >> 1) & 1), ntw = 3 - (cls & 1);
        const char* tbb = (const char*)wtp + (size_t)cls * 27 * 4096 + laneB;
        const int T = ntd * nth * ntw;   // >= 8 always

        f32x4 acc[3][2][4];
#pragma unroll
        for (int b = 0; b < 3; ++b)
#pragma unroll
            for (int mt = 0; mt < 2; ++mt)
#pragma unroll
                for (int nt = 0; nt < 4; ++nt) acc[b][mt][nt] = (f32x4){0.f, 0.f, 0.f, 0.f};

        int ptd = 0, pth = 0, ptw = 0;   // state = next unissued tap
        auto adv = [&]() {
            ++ptw;
            if (ptw == ntw) { ptw = 0; ++pth; if (pth == nth) { pth = 0; ++ptd; } }
        };

        // ---- prologue: load A+B for tap 0 (E) ----
        bf16x8 bE0, bE1, bE2, bE3, aE0, aE1, aE2, aE3, aE4, aE5;
        {
            int Qb = ((alpha + 2) * 5 + 2) * 2048;        // ss = 2
            bE0 = *(const bf16x8*)(tbb);
            bE1 = *(const bf16x8*)(tbb + 1024);
            bE2 = *(const bf16x8*)(tbb + 2048);
            bE3 = *(const bf16x8*)(tbb + 3072);
            const char* rb = xsb + Qb;
            aE0 = *(const bf16x8*)(rb + lp02);
            aE1 = *(const bf16x8*)(rb + lp12);
            aE2 = *(const bf16x8*)(rb + 2048 + lp02);
            aE3 = *(const bf16x8*)(rb + 2048 + lp12);
            aE4 = *(const bf16x8*)(rb + 4096 + lp02);
            aE5 = *(const bf16x8*)(rb + 4096 + lp12);
        }
        adv();
        // ---- load A+B for tap 1 (O) ----
        bf16x8 bO0, bO1, bO2, bO3, aO0, aO1, aO2, aO3, aO4, aO5;
        {
            int Qb = ((alpha + 2 - ptd) * 5 + (2 - pth)) * 2048;
            int ss = 2 - ptw;
            const char* bq = tbb + (ptd * 9 + pth * 3 + ptw) * 4096;
            bO0 = *(const bf16x8*)(bq);
            bO1 = *(const bf16x8*)(bq + 1024);
            bO2 = *(const bf16x8*)(bq + 2048);
            bO3 = *(const bf16x8*)(bq + 3072);
            int lpa = ss == 0 ? lp00 : (ss == 1 ? lp01 : lp02);
            int lpb = ss == 0 ? lp10 : (ss == 1 ? lp11 : lp12);
            const char* rb = xsb + Qb;
            aO0 = *(const bf16x8*)(rb + lpa);
            aO1 = *(const bf16x8*)(rb + lpb);
            aO2 = *(const bf16x8*)(rb + 2048 + lpa);
            aO3 = *(const bf16x8*)(rb + 2048 + lpb);
            aO4 = *(const bf16x8*)(rb + 4096 + lpa);
            aO5 = *(const bf16x8*)(rb + 4096 + lpb);
        }
        adv();

#pragma unroll 1
        for (int it = 0; it < T; it += 2) {
            // ---- consume E (tap it), nt-major; reload bEj for tap it+2 right
            //      after its last use in this burst (stretches B load->use distance) ----
            bool moreE = (it + 2 < T);
            int nBoff = 0, nQb = 0, nSs = 0;
            __builtin_amdgcn_s_setprio(1);
            MFMA_G(0, E)
            if (moreE) {
                nBoff = __builtin_amdgcn_readfirstlane((ptd * 9 + pth * 3 + ptw) * 4096);
                nQb   = __builtin_amdgcn_readfirstlane(((alpha + 2 - ptd) * 5 + (2 - pth)) * 2048);
                nSs   = __builtin_amdgcn_readfirstlane(2 - ptw);
                bE0 = *(const bf16x8*)(tbb + nBoff);
            }
            MFMA_G(1, E)
            if (moreE) bE1 = *(const bf16x8*)(tbb + nBoff + 1024);
            MFMA_G(2, E)
            if (moreE) bE2 = *(const bf16x8*)(tbb + nBoff + 2048);
            MFMA_G(3, E)
            __builtin_amdgcn_s_setprio(0);
            if (moreE) {
                bE3 = *(const bf16x8*)(tbb + nBoff + 3072);
                int lpa = nSs == 0 ? lp00 : (nSs == 1 ? lp01 : lp02);
                int lpb = nSs == 0 ? lp10 : (nSs == 1 ? lp11 : lp12);
                const char* rb = xsb + nQb;
                aE0 = *(const bf16x8*)(rb + lpa);
                aE1 = *(const bf16x8*)(rb + lpb);
                aE2 = *(const bf16x8*)(rb + 2048 + lpa);
                aE3 = *(const bf16x8*)(rb + 2048 + lpb);
                aE4 = *(const bf16x8*)(rb + 4096 + lpa);
                aE5 = *(const bf16x8*)(rb + 4096 + lpb);
                adv();
            }
            if (it + 1 < T) {
                // ---- consume O (tap it+1), same interleave for tap it+3 ----
                bool moreO = (it + 3 < T);
                int oBoff = 0, oQb = 0, oSs = 0;
                __builtin_amdgcn_s_setprio(1);
                MFMA_G(0, O)
                if (moreO) {
                    oBoff = __builtin_amdgcn_readfirstlane((ptd * 9 + pth * 3 + ptw) * 4096);
                    oQb   = __builtin_amdgcn_readfirstlane(((alpha + 2 - ptd) * 5 + (2 - pth)) * 2048);
                    oSs   = __builtin_amdgcn_readfirstlane(2 - ptw);
                    bO0 = *(const bf16x8*)(tbb + oBoff);
                }
                MFMA_G(1, O)
                if (moreO) bO1 = *(const bf16x8*)(tbb + oBoff + 1024);
                MFMA_G(2, O)
                if (moreO) bO2 = *(const bf16x8*)(tbb + oBoff + 2048);
                MFMA_G(3, O)
                __builtin_amdgcn_s_setprio(0);
                if (moreO) {
                    bO3 = *(const bf16x8*)(tbb + oBoff + 3072);
                    int lpa = oSs == 0 ? lp00 : (oSs == 1 ? lp01 : lp02);
                    int lpb = oSs == 0 ? lp10 : (oSs == 1 ? lp11 : lp12);
                    const char* rb = xsb + oQb;
                    aO0 = *(const bf16x8*)(rb + lpa);
                    aO1 = *(const bf16x8*)(rb + lpb);
                    aO2 = *(const bf16x8*)(rb + 2048 + lpa);
                    aO3 = *(const bf16x8*)(rb + 2048 + lpb);
                    aO4 = *(const bf16x8*)(rb + 4096 + lpa);
                    aO5 = *(const bf16x8*)(rb + 4096 + lpb);
                    adv();
                }
            }
        }

        // fold item into running max (same (m,co) mapping for every item)
#pragma unroll
        for (int mt = 0; mt < 2; ++mt)
#pragma unroll
            for (int nt = 0; nt < 4; ++nt)
#pragma unroll
                for (int r = 0; r < 4; ++r) {
                    float m = fmaxf(fmaxf(acc[0][mt][nt][r], acc[1][mt][nt][r]), acc[2][mt][nt][r]);
                    mx[mt][nt][r] = fmaxf(mx[mt][nt][r], m);
                }
    }

    // ---- epilogue: gamma->window fold, cross-wave max, bias, co-sum ----
    __syncthreads();                 // Xs reads done; reuse as epi buffer
    float* epi = (float*)Xs;
    int fsm0 = (0x3123 >> (quad * 4)) & 15;
    int fsm1 = (0x4312 >> (quad * 4)) & 15;
#pragma unroll
    for (int mt = 0; mt < 2; ++mt) {
        int fs = mt ? fsm1 : fsm0;
        int g  = mt * 4 + quad;
#pragma unroll
        for (int nt = 0; nt < 4; ++nt) {
            float a0 = mx[mt][nt][0], a1 = mx[mt][nt][1], a2 = mx[mt][nt][2], a3 = mx[mt][nt][3];
            float t01 = fmaxf(a0, a1), t012 = fmaxf(t01, a2), t0123 = fmaxf(t012, a3);
            float pA = fs == 1 ? a0 : (fs == 2 ? t01 : (fs == 3 ? t012 : t0123));
            float t23 = fmaxf(a2, a3), t123 = fmaxf(a1, t23);
            float pB = fs == 1 ? t123 : (fs == 2 ? t23 : (fs == 3 ? a3 : -INFINITY));
            epi[((wv * 8 + g) * 2 + 0) * 64 + nt * 16 + l15] = pA;
            epi[((wv * 8 + g) * 2 + 1) * 64 + nt * 16 + l15] = pB;
        }
    }
    __syncthreads();

    int elemBase = ((n * 5 + d0) * 10 + h0) * 10;
    float bco = bias[lane];
#pragma unroll 1
    for (int win = wv_s; win < 10; win += 4) {
        int st = EPI_START[win], cnt = EPI_CNT[win];
        float v = -INFINITY;
        for (int src = 0; src < 4; ++src)
            for (int e = st; e < st + cnt; ++e)
                v = fmaxf(v, epi[(src * 16 + e) * 64 + lane]);
        v += bco;
#pragma unroll
        for (int off = 32; off > 0; off >>= 1) v += __shfl_xor(v, off);
        if (lane == 0) out[elemBase + win] = v;
    }
}

// ---------------- fallback (round-1 kernel, no ws needed) ----------------
__global__ __launch_bounds__(256) void fused_fallback(
    const float* __restrict__ x, const float* __restrict__ wsrc,
    const float* __restrict__ bias, float* __restrict__ out)
{
    __shared__ float xs[CIN * 125];
    __shared__ float wmax[4][64];
    const int b  = blockIdx.x;
    const int w0 = b % 10, h0 = (b / 10) % 10, d0 = (b / 100) % 5, n = b / 500;
    const int tid = threadIdx.x;
    const int id0 = 3 * d0 - 1, ih0 = 3 * h0 - 1, iw0 = 3 * w0 - 1;
    for (int e = tid; e < CIN * 125; e += 256) {
        int kk = e % 5, jj = (e / 5) % 5, ii = (e / 25) % 5, c = e / 125;
        int id = id0 + ii, ih = ih0 + jj, iw = iw0 + kk;
        float v = 0.f;
        if (id >= 0 && ih >= 0 && iw >= 0)
            v = x[(((n * CIN + c) * D + id) * H + ih) * W + iw];
        xs[e] = v;
    }
    __syncthreads();
    const int lane = tid & 63, wv = tid >> 6;
    float lmax = -INFINITY;
    for (int ccls = 0; ccls < 2; ++ccls) {
        const int cls = wv * 2 + ccls;
        const int pd = (cls >> 2) & 1, ph = (cls >> 1) & 1, pw = cls & 1;
        float acc[27];
#pragma unroll
        for (int i = 0; i < 27; ++i) acc[i] = 0.f;
        for (int ci = 0; ci < CIN; ++ci) {
            float wr[27];
#pragma unroll
            for (int t = 0; t < 27; ++t) {
                int td = t / 9, th = (t / 3) % 3, tw = t % 3;
                int kd = pd + 2 * td, kh = ph + 2 * th, kw = pw + 2 * tw;
                wr[t] = (kd < 5 && kh < 5 && kw < 5)
                          ? wsrc[((ci * 64 + lane) * 125) + kd * 25 + kh * 5 + kw] : 0.f;
            }
            const float* xb = xs + ci * 125;
#pragma unroll
            for (int td = 0; td < 3; ++td)
#pragma unroll
            for (int th = 0; th < 3; ++th)
#pragma unroll
            for (int tw = 0; tw < 3; ++tw) {
                const float wval = wr[(td * 3 + th) * 3 + tw];
#pragma unroll
                for (int a = 0; a < 3; ++a)
#pragma unroll
                for (int bb = 0; bb < 3; ++bb)
#pragma unroll
                for (int cc = 0; cc < 3; ++cc)
                    acc[(a * 3 + bb) * 3 + cc] +=
                        xb[(a + 2 - td) * 25 + (bb + 2 - th) * 5 + (cc + 2 - tw)] * wval;
            }
        }
#pragma unroll
        for (int i = 0; i < 27; ++i) lmax = fmaxf(lmax, acc[i]);
    }
    wmax[wv][lane] = lmax;
    __syncthreads();
    if (wv == 0) {
        float m = fmaxf(fmaxf(wmax[0][lane], wmax[1][lane]),
                        fmaxf(wmax[2][lane], wmax[3][lane]));
        m += bias[lane];
        for (int off = 32; off > 0; off >>= 1) m += __shfl_down(m, off);
        if (lane == 0) out[b] = m;
    }
}

extern "C" void kernel_launch(void* const* d_in, const int* in_sizes, int n_in,
                              void* d_out, int out_size, void* d_ws, size_t ws_size,
                              hipStream_t stream) {
    const float* x    = (const float*)d_in[0];
    const float* w    = (const float*)d_in[1];
    const float* bias = (const float*)d_in[2];
    float* out = (float*)d_out;

    if (ws_size >= WS_NEED) {
        unsigned short* wtp = (unsigned short*)d_ws;
        prep_w<<<1728, 256, 0, stream>>>(w, wtp);
        main_k<<<800, 256, 0, stream>>>(wtp, x, bias, out);
    } else {
        fused_fallback<<<8000, 256, 0, stream>>>(x, w, bias, out);
    }
}